// Round 16
// baseline (131.536 us; speedup 1.0000x reference)
//
#include <hip/hip_runtime.h>

// PWC-Net correlation (md=4, 81 disps) + leaky_relu(0.1), mean over C=256.
// B=8 C=256 H=96 W=128, f32 in/out.
//
// R16: MFMA engine on the R12 chassis. R15 disproved phase-overhead as the
// bottleneck; R12 is LDS-instruction-bound (~43-70us of 82). MFMA cuts LDS
// reads 2.5x (fragment reads amortize over 16x16 tiles) and moves 25us of
// dot2 VALU to ~7us of matrix pipe.
// Tile = 2h x 64w x 3dy, block 3 waves (192 thr), wave = dy-in-group.
// Grid 8(b==XCD) x 96(h-tile*2+whalf) x 3(dg) = 2304 blocks, 4/CU resident.
// Per wave per 32ch slice: 16 x mfma_f32_16x16x32_f16 (8 Mtiles x {L,H}
// dx-band N-tiles, B-tiles shared via sliding window), 8 A + 10 B b128
// fragment reads. A and B staged with IDENTICAL [px][chpair] layout so any
// k-permutation cancels (R13 refcheck-verified); C/D col=lane&15,
// row=(lane>>4)*4+reg (R13-verified). px-stride 20 u32: b128-aligned,
// bank floor. x2 rows 0..3 serve (hr,dy): row = hr+wid. Invalid pad quads
// zero-written per slice.
// Lessons: R13 tiny tiles -> FETCH 4x (fixed: 2h tile + whalf-adjacent
// ordering); spills fatal (sentinel WRITE_SIZE >> 31MB); acc must land in
// AGPRs (m97/m98 show compiler does this for MFMA acc on gfx950).

#define B_ 8
#define C_ 256
#define H_ 96
#define W_ 128
#define HW (H_ * W_)
#define NSL 8                     // K-slices of 32 channels
#define PXST 20                   // u32 stride per pixel (16 data + 4 pad)
#define X1O 0                     // x1: 128 px (2 rows x 64 w)
#define X2O (128 * PXST)          // 2560
#define X2RS (80 * PXST)          // 1600 u32/row (72 staged + 8 alloc pad)
#define SMSZ (X2O + 4 * X2RS)     // 8960 u32 = 35.84 KB
#define NTHR 192
#define NTASK 416                 // 128 x1 + 288 x2 wide tasks per slice

typedef __fp16 f16x8 __attribute__((ext_vector_type(8)));
typedef float  f32x4 __attribute__((ext_vector_type(4)));
typedef __fp16 h2_t  __attribute__((ext_vector_type(2)));
union H2U { unsigned int u; h2_t h; };

__device__ __forceinline__ unsigned int packh2(float a, float b) {
    H2U x; x.h = __builtin_amdgcn_cvt_pkrtz(a, b); return x.u;
}

__global__ __attribute__((amdgpu_flat_work_group_size(NTHR, NTHR)))
void corr_kernel(const float* __restrict__ x1, const float* __restrict__ x2,
                 float* __restrict__ out)
{
    __shared__ __align__(16) unsigned int smem[SMSZ];

    const int b   = blockIdx.x;         // batch == XCD (x fastest)
    const int h0  = (blockIdx.y >> 1) * 2;
    const int w0  = (blockIdx.y & 1) * 64;   // whalf adjacent in dispatch
    const int dg  = blockIdx.z;         // dy = 3*dg + wid
    const int tid = threadIdx.x;
    const int wid = tid >> 6;
    const int lane = tid & 63;
    const int l15 = lane & 15, g = lane >> 4;

    // ---------------- staging descriptors: 3 rounds x 192 threads ----------
    // u<128: x1. p=u>>5 (8ch plane), q=u&31: rx=q>>4, w4=q&15 -> 4px quad.
    // 128<=u<416: x2. v=u-128: p=v&3, q=v>>2: w18=q%18 (4px quad of 72),
    //   r=q/18 (row 0..3). Invalid (h or w edge) -> zero-write each slice.
    // LDS: px*PXST + p*4 (+k*PXST per px). One uint4 = 4 chpairs of one px.
    unsigned off_[3]; int sb_[3]; int mval = 0, mzero = 0, msrc = 0;
    #pragma unroll
    for (int r3 = 0; r3 < 3; ++r3) {
        const int u = tid + NTHR * r3;
        unsigned off = 0; int sb = 0; bool val = false, zero = false, sx2 = false;
        if (u < 128) {
            const int p = u >> 5, q = u & 31;
            const int rx = q >> 4, w4 = q & 15;
            off = (unsigned)(b * C_ + 8 * p) * HW
                + (unsigned)((h0 + rx) * W_ + w0 + 4 * w4);
            sb = X1O + (rx * 64 + 4 * w4) * PXST + p * 4;
            val = true;
        } else if (u < NTASK) {
            const int v = u - 128;
            const int p = v & 3, q = v >> 2;
            const int w18 = q % 18, r = q / 18;
            const int h2 = h0 + 3 * dg + r - 4;
            const bool okh = (h2 >= 0) && (h2 < H_);
            const bool okw = !((w0 == 0) && (w18 == 0)) &&
                             !((w0 == 64) && (w18 == 17));
            val = okh && okw;
            zero = !val;
            off = (unsigned)(b * C_ + 8 * p) * HW
                + (unsigned)((val ? h2 : 0) * W_ + (val ? (w0 - 4 + 4 * w18) : 0));
            sb = X2O + r * X2RS + (4 * w18) * PXST + p * 4;
            sx2 = true;
        }
        off_[r3] = off; sb_[r3] = sb;
        mval |= (int)val << r3; mzero |= (int)zero << r3; msrc |= (int)sx2 << r3;
    }

    auto STAGE = [&](int ss) {
        const unsigned co = (unsigned)ss * (32u * HW);
        #pragma unroll
        for (int r3 = 0; r3 < 3; ++r3) {
            if ((mval >> r3) & 1) {
                const float* p = (((msrc >> r3) & 1) ? x2 : x1) + off_[r3] + co;
                const float4 f0 = *reinterpret_cast<const float4*>(p);
                const float4 f1 = *reinterpret_cast<const float4*>(p + HW);
                const float4 f2 = *reinterpret_cast<const float4*>(p + 2 * HW);
                const float4 f3 = *reinterpret_cast<const float4*>(p + 3 * HW);
                const float4 f4 = *reinterpret_cast<const float4*>(p + 4 * HW);
                const float4 f5 = *reinterpret_cast<const float4*>(p + 5 * HW);
                const float4 f6 = *reinterpret_cast<const float4*>(p + 6 * HW);
                const float4 f7 = *reinterpret_cast<const float4*>(p + 7 * HW);
                const int sb = sb_[r3];
                uint4 wv;
                wv.x = packh2(f0.x, f1.x); wv.y = packh2(f2.x, f3.x);
                wv.z = packh2(f4.x, f5.x); wv.w = packh2(f6.x, f7.x);
                *reinterpret_cast<uint4*>(&smem[sb]) = wv;
                wv.x = packh2(f0.y, f1.y); wv.y = packh2(f2.y, f3.y);
                wv.z = packh2(f4.y, f5.y); wv.w = packh2(f6.y, f7.y);
                *reinterpret_cast<uint4*>(&smem[sb + PXST]) = wv;
                wv.x = packh2(f0.z, f1.z); wv.y = packh2(f2.z, f3.z);
                wv.z = packh2(f4.z, f5.z); wv.w = packh2(f6.z, f7.z);
                *reinterpret_cast<uint4*>(&smem[sb + 2 * PXST]) = wv;
                wv.x = packh2(f0.w, f1.w); wv.y = packh2(f2.w, f3.w);
                wv.z = packh2(f4.w, f5.w); wv.w = packh2(f6.w, f7.w);
                *reinterpret_cast<uint4*>(&smem[sb + 3 * PXST]) = wv;
            } else if ((mzero >> r3) & 1) {
                const uint4 zz = {0u, 0u, 0u, 0u};
                const int sb = sb_[r3];
                *reinterpret_cast<uint4*>(&smem[sb])            = zz;
                *reinterpret_cast<uint4*>(&smem[sb + PXST])     = zz;
                *reinterpret_cast<uint4*>(&smem[sb + 2 * PXST]) = zz;
                *reinterpret_cast<uint4*>(&smem[sb + 3 * PXST]) = zz;
            }
        }
    };

    // ---------------- accumulators: 16 x f32x4 (expect AGPR) ---------------
    f32x4 accL[2][4], accH[2][4];
    #pragma unroll
    for (int rm = 0; rm < 2; ++rm)
        #pragma unroll
        for (int t = 0; t < 4; ++t) {
            accL[rm][t] = (f32x4){0.f, 0.f, 0.f, 0.f};
            accH[rm][t] = (f32x4){0.f, 0.f, 0.f, 0.f};
        }

    // ---------------- K-slice loop: stage; sync; mfma; sync ----------------
    #pragma unroll 1
    for (int ss = 0; ss < NSL; ++ss) {
        STAGE(ss);
        __syncthreads();
        #pragma unroll
        for (int rm = 0; rm < 2; ++rm) {
            const int brow = rm + wid;         // staged x2 row 0..3
            const int bb = X2O + brow * X2RS;
            f16x8 Bt[5];
            #pragma unroll
            for (int j = 0; j < 5; ++j)
                Bt[j] = *reinterpret_cast<const f16x8*>(
                    &smem[bb + (16 * j + l15) * PXST + g * 4]);
            #pragma unroll
            for (int mtw = 0; mtw < 4; ++mtw) {
                const f16x8 Av = *reinterpret_cast<const f16x8*>(
                    &smem[X1O + (rm * 64 + 16 * mtw + l15) * PXST + g * 4]);
                accL[rm][mtw] = __builtin_amdgcn_mfma_f32_16x16x32_f16(
                    Av, Bt[mtw],     accL[rm][mtw], 0, 0, 0);
                accH[rm][mtw] = __builtin_amdgcn_mfma_f32_16x16x32_f16(
                    Av, Bt[mtw + 1], accH[rm][mtw], 0, 0, 0);
            }
        }
        __syncthreads();
    }

    // ---------------- epilogue: scatter acc -> LDS, coalesced stores -------
    // D layout: col n = l15, row m = 4g+reg. L: d = n-m; H: d = 16+n-m.
    // ep[wave][d][rm][w]: idx = wave*1152 + d*128 + rm*64 + w.
    float* const smf = reinterpret_cast<float*>(smem);
    const int eb = wid * 1152;
    #pragma unroll
    for (int rm = 0; rm < 2; ++rm)
        #pragma unroll
        for (int mtw = 0; mtw < 4; ++mtw)
            #pragma unroll
            for (int reg = 0; reg < 4; ++reg) {
                const int m = 4 * g + reg;
                const int w = 16 * mtw + m;
                const int dL = l15 - m;
                if (dL >= 0 && dL <= 8)
                    smf[eb + dL * 128 + rm * 64 + w] = accL[rm][mtw][reg];
                const int dH = 16 + l15 - m;
                if (dH <= 8)
                    smf[eb + dH * 128 + rm * 64 + w] = accH[rm][mtw][reg];
            }
    __syncthreads();

    const float inv = 1.0f / 256.0f;
    #pragma unroll
    for (int r5 = 0; r5 < 5; ++r5) {
        const int u = tid + NTHR * r5;
        if (u < 864) {                       // 54 groups x 16 float4
            const int fidx = u & 15;
            const int grp  = u >> 4;         // 0..53
            const int rm   = grp & 1;
            const int t9   = grp >> 1;       // 0..26
            const int d    = t9 % 9, wv = t9 / 9;
            const float4 v = *reinterpret_cast<const float4*>(
                &smf[wv * 1152 + d * 128 + rm * 64 + 4 * fidx]);
            float4 o; float s;
            s = v.x * inv; o.x = s >= 0.f ? s : 0.1f * s;
            s = v.y * inv; o.y = s >= 0.f ? s : 0.1f * s;
            s = v.z * inv; o.z = s >= 0.f ? s : 0.1f * s;
            s = v.w * inv; o.w = s >= 0.f ? s : 0.1f * s;
            float* dst = out + ((size_t)(b * 81 + (3 * dg + wv) * 9 + d)) * HW
                       + (size_t)(h0 + rm) * W_ + w0 + 4 * fidx;
            *reinterpret_cast<float4*>(dst) = o;
        }
    }
}

extern "C" void kernel_launch(void* const* d_in, const int* in_sizes, int n_in,
                              void* d_out, int out_size, void* d_ws, size_t ws_size,
                              hipStream_t stream) {
    const float* x1 = (const float*)d_in[0];
    const float* x2 = (const float*)d_in[1];
    float* out = (float*)d_out;
    corr_kernel<<<dim3(B_, 96, 3), dim3(NTHR), 0, stream>>>(x1, x2, out);
}

// Round 17
// 119.471 us; speedup vs baseline: 1.1010x; 1.1010x over previous
//
#include <hip/hip_runtime.h>

// PWC-Net correlation (md=4, 81 disps) + leaky_relu(0.1), mean over C=256.
// B=8 C=256 H=96 W=128, f32 in/out.
//
// R17 = R12 (champion, 82us) with X1 SELF-PACKED IN REGISTERS:
// each compute lane loads+packs its OWN 4px x 8ch x1 fragment per chunk
// (8 float4 -> 16 packh2 -> x1v[4] uint4 in VGPRs). x1 LDS reads (4 of 16
// per lane-chunk) and x1 LDS writes disappear -> LDS pipe ~43 -> ~32us.
// x1 global loads go 1x -> 3x, but the 3 readers are the SAME block's
// waves in the SAME phase (8KB slice, L1-resident) -- unlike R8, where
// the duplicate readers were distant blocks (FETCH 2.5x, 227us).
// x2 staging: 128 wide tasks (4 rows x 32 quads) over 192 threads,
// R12's task shape verbatim. Compute/swizzle/epilogue: R12 verbatim.
// Block = 3 waves (192 thr), wave = dy of 3-dy group; grid =
// 8(b==XCD) x 48(h-tiles) x 3(dg) = 1152.
// Lessons: spills fatal (sentinel WRITE_SIZE >> 31MB); MFMA starves at
// this staging:compute ratio (R13/R16); phase reordering null/regress
// (R9/R10/R15); barrier-free loses to shared staging (R14).

#define B_ 8
#define C_ 256
#define H_ 96
#define W_ 128
#define TH 2
#define CC 8
#define NCH (C_ / CC)            // 32 chunks
#define HW (H_ * W_)
#define CHSTRIDE (CC * HW)       // floats, fits u32
#define S2SZ (4 * 544)           // 2176 u32 (4 staged x2 rows) = 8.7 KB
#define NTHR 192

typedef __fp16 h2_t __attribute__((ext_vector_type(2)));
union H2U { unsigned int u; h2_t h; };

__device__ __forceinline__ h2_t u_as_h2(unsigned int u) { H2U x; x.u = u; return x.h; }

__device__ __forceinline__ unsigned int packh2(float a, float b) {
    H2U x; x.h = __builtin_amdgcn_cvt_pkrtz(a, b); return x.u;
}

#if __has_builtin(__builtin_amdgcn_fdot2)
__device__ __forceinline__ float dot2(unsigned int a, unsigned int b, float c) {
    return __builtin_amdgcn_fdot2(u_as_h2(a), u_as_h2(b), c, false);
}
#else
__device__ __forceinline__ float dot2(unsigned int a, unsigned int b, float c) {
    h2_t ha = u_as_h2(a), hb = u_as_h2(b);
    return c + (float)ha[0] * (float)hb[0] + (float)ha[1] * (float)hb[1];
}
#endif

__global__ __attribute__((amdgpu_flat_work_group_size(NTHR, NTHR)))
void corr_kernel(const float* __restrict__ x1, const float* __restrict__ x2,
                 float* __restrict__ out)
{
    __shared__ __align__(16) unsigned int smem[S2SZ];   // x2 only

    const int b   = blockIdx.x;       // batch == XCD (x fastest => round-robin)
    const int h0  = blockIdx.y * TH;
    const int dg  = blockIdx.z;       // dy = 3*dg + wid
    const int tid = threadIdx.x;
    const int wid = tid >> 6;         // 0..2
    const int lane = tid & 63;
    const int hr  = lane >> 5;        // 0..1
    const int wq  = lane & 31;        // 32 groups of 4 w pixels

    // ---------------- x1 self descriptor (own 4px, row h0+hr) --------------
    const unsigned o1 =
        (unsigned)(b * C_) * HW + (unsigned)((h0 + hr) * W_ + 4 * wq);

    // ---------------- x2 staging task: threads 0..127, one wide task -------
    // r=tid>>5 (0..3), g=(tid&31)+1 (1..32; pad quads g=0/33 stay zero).
    // LDS u32 idx for slot s, ch-pair cp, row r:
    //   r*544 + (s>>3)*32 + (((s&7)^((s>>3)&7)^(r&7))<<2) + cp
    const bool x2act = (tid < 128);
    const int r2 = (tid >> 5) & 3;
    const int g  = (tid & 31) + 1;
    const int h2 = h0 + 3 * dg + r2 - 4;
    const bool val2 = x2act && (h2 >= 0) && (h2 < H_);
    const unsigned off2 = (unsigned)(b * C_) * HW
        + (unsigned)((val2 ? h2 : 0) * W_ + 4 * g - 4);
    const int c2 = r2 * 544 + (g >> 1) * 32;
    const int X2 = (4 * (g & 1)) ^ ((g >> 1) & 7) ^ (r2 & 7);

    // ---------------- compute setup (R12 verbatim) ----------------
    const int row = hr + wid;              // staged x2 row 0..3
    int a2p[6];                            // 12 chunk-invariant addrs, 2x16b
    #pragma unroll
    for (int t = 0; t < 12; t += 2) {
        const int s0 = 4 * wq + t, s1 = s0 + 1;
        const int A0 = row * 544 + (s0 >> 3) * 32
                     + (((s0 & 7) ^ ((s0 >> 3) & 7) ^ row) << 2);
        const int A1 = row * 544 + (s1 >> 3) * 32
                     + (((s1 & 7) ^ ((s1 >> 3) & 7) ^ row) << 2);
        a2p[t >> 1] = A0 | (A1 << 16);
    }

    float acc[4][9];
    #pragma unroll
    for (int p = 0; p < 4; ++p)
        #pragma unroll
        for (int d = 0; d < 9; ++d) acc[p][d] = 0.f;

    // zero all of s2 once (covers pad quads g=0/33 and invalid rows)
    for (int i = tid; i < S2SZ; i += NTHR) smem[i] = 0u;
    __syncthreads();

    // ---------------- chunk loop: stage; sync; compute; sync ---------------
    #pragma unroll 1
    for (int cc = 0; cc < NCH; ++cc) {
        const unsigned co = (unsigned)cc * (unsigned)CHSTRIDE;

        // x1 self-load + pack into registers (two quartets, short ranges)
        uint4 x1v[4];
        {
            const float* p1 = x1 + o1 + co;
            const float4 f0 = *reinterpret_cast<const float4*>(p1);
            const float4 f1 = *reinterpret_cast<const float4*>(p1 + HW);
            const float4 f2 = *reinterpret_cast<const float4*>(p1 + 2 * HW);
            const float4 f3 = *reinterpret_cast<const float4*>(p1 + 3 * HW);
            x1v[0].x = packh2(f0.x, f1.x); x1v[1].x = packh2(f0.y, f1.y);
            x1v[2].x = packh2(f0.z, f1.z); x1v[3].x = packh2(f0.w, f1.w);
            x1v[0].y = packh2(f2.x, f3.x); x1v[1].y = packh2(f2.y, f3.y);
            x1v[2].y = packh2(f2.z, f3.z); x1v[3].y = packh2(f2.w, f3.w);
        }
        {
            const float* p1 = x1 + o1 + co + 4 * HW;
            const float4 f4 = *reinterpret_cast<const float4*>(p1);
            const float4 f5 = *reinterpret_cast<const float4*>(p1 + HW);
            const float4 f6 = *reinterpret_cast<const float4*>(p1 + 2 * HW);
            const float4 f7 = *reinterpret_cast<const float4*>(p1 + 3 * HW);
            x1v[0].z = packh2(f4.x, f5.x); x1v[1].z = packh2(f4.y, f5.y);
            x1v[2].z = packh2(f4.z, f5.z); x1v[3].z = packh2(f4.w, f5.w);
            x1v[0].w = packh2(f6.x, f7.x); x1v[1].w = packh2(f6.y, f7.y);
            x1v[2].w = packh2(f6.z, f7.z); x1v[3].w = packh2(f6.w, f7.w);
        }

        // x2 wide staging task (threads 0..127)
        if (val2) {
            const float* p = x2 + off2 + co;
            const float4 f0 = *reinterpret_cast<const float4*>(p);
            const float4 f1 = *reinterpret_cast<const float4*>(p + HW);
            const float4 f2 = *reinterpret_cast<const float4*>(p + 2 * HW);
            const float4 f3 = *reinterpret_cast<const float4*>(p + 3 * HW);
            const float4 f4 = *reinterpret_cast<const float4*>(p + 4 * HW);
            const float4 f5 = *reinterpret_cast<const float4*>(p + 5 * HW);
            const float4 f6 = *reinterpret_cast<const float4*>(p + 6 * HW);
            const float4 f7 = *reinterpret_cast<const float4*>(p + 7 * HW);
            uint4 wv;
            wv.x = packh2(f0.x, f1.x); wv.y = packh2(f2.x, f3.x);
            wv.z = packh2(f4.x, f5.x); wv.w = packh2(f6.x, f7.x);
            *reinterpret_cast<uint4*>(&smem[c2 + ((0 ^ X2) << 2)]) = wv;
            wv.x = packh2(f0.y, f1.y); wv.y = packh2(f2.y, f3.y);
            wv.z = packh2(f4.y, f5.y); wv.w = packh2(f6.y, f7.y);
            *reinterpret_cast<uint4*>(&smem[c2 + ((1 ^ X2) << 2)]) = wv;
            wv.x = packh2(f0.z, f1.z); wv.y = packh2(f2.z, f3.z);
            wv.z = packh2(f4.z, f5.z); wv.w = packh2(f6.z, f7.z);
            *reinterpret_cast<uint4*>(&smem[c2 + ((2 ^ X2) << 2)]) = wv;
            wv.x = packh2(f0.w, f1.w); wv.y = packh2(f2.w, f3.w);
            wv.z = packh2(f4.w, f5.w); wv.w = packh2(f6.w, f7.w);
            *reinterpret_cast<uint4*>(&smem[c2 + ((3 ^ X2) << 2)]) = wv;
        }
        __syncthreads();

        #pragma unroll
        for (int t = 0; t < 12; ++t) {
            const int ad = (t & 1) ? (a2p[t >> 1] >> 16) : (a2p[t >> 1] & 0xffff);
            const uint4 x2v = *reinterpret_cast<const uint4*>(&smem[ad]);
            #pragma unroll
            for (int p = 0; p < 4; ++p) {
                const int dxx = t - p;          // compile-time after unroll
                if (dxx >= 0 && dxx <= 8) {
                    float a = acc[p][dxx];
                    a = dot2(x1v[p].x, x2v.x, a);
                    a = dot2(x1v[p].y, x2v.y, a);
                    a = dot2(x1v[p].z, x2v.z, a);
                    a = dot2(x1v[p].w, x2v.w, a);
                    acc[p][dxx] = a;
                }
            }
        }
        __syncthreads();
    }

    // ---------------- epilogue: mean + leaky_relu + coalesced f32x4 writes -
    const float inv = 1.0f / 256.0f;
    const int dy = 3 * dg + wid;
    float* ob = out + (((size_t)(b * 81 + dy * 9)) * H_ + (h0 + hr)) * W_ + wq * 4;
    #pragma unroll
    for (int dxx = 0; dxx < 9; ++dxx) {
        float4 o;
        float v;
        v = acc[0][dxx] * inv; o.x = v >= 0.f ? v : 0.1f * v;
        v = acc[1][dxx] * inv; o.y = v >= 0.f ? v : 0.1f * v;
        v = acc[2][dxx] * inv; o.z = v >= 0.f ? v : 0.1f * v;
        v = acc[3][dxx] * inv; o.w = v >= 0.f ? v : 0.1f * v;
        *reinterpret_cast<float4*>(ob + (size_t)dxx * HW) = o;
    }
}

extern "C" void kernel_launch(void* const* d_in, const int* in_sizes, int n_in,
                              void* d_out, int out_size, void* d_ws, size_t ws_size,
                              hipStream_t stream) {
    const float* x1 = (const float*)d_in[0];
    const float* x2 = (const float*)d_in[1];
    float* out = (float*)d_out;
    corr_kernel<<<dim3(B_, H_ / TH, 3), dim3(NTHR), 0, stream>>>(x1, x2, out);
}